// Round 3
// baseline (13490.941 us; speedup 1.0000x reference)
//
#include <hip/hip_runtime.h>

// Problem constants (from reference)
constexpr int B_ = 16, T_ = 128, S_ = 128;
constexpr int ROWS = B_ * S_;        // 2048
constexpr int NSTEPS = T_ - 1;       // 127
constexpr int TPRED = 20;
constexpr int TOUT = NSTEPS - TPRED; // 107
constexpr int RPB = 8;               // rows per block (blocks never straddle a batch)
constexpr int TB = 1024;             // 16 waves/CU at grid=256 (1 block/CU)
constexpr int NBLK = ROWS / RPB;     // 256

// ws layout (floats):
// flags[256] (int), halo[256 blk][2 slot][2 side][256], outs[127][2048][2]
constexpr int OFF_FLAGS = 0;
constexpr int OFF_HALO = 256;
constexpr int HALO_SZ = NBLK * 2 * 2 * 256;
constexpr int OFF_OUTS = OFF_HALO + HALO_SZ;
constexpr int ZERO_FLOATS = OFF_OUTS;   // zero flags+halo each call

__device__ __forceinline__ float sigm(float x) { return 1.f / (1.f + __expf(-x)); }
__device__ __forceinline__ float tanh_(float x) { return 2.f / (1.f + __expf(-2.f * x)) - 1.f; }

__global__ __launch_bounds__(TB) void persist_kernel(
    const float* __restrict__ input,
    const float* __restrict__ nWx, const float* __restrict__ nWh,
    const float* __restrict__ nWa, const float* __restrict__ nWb, const float* __restrict__ nb,
    const float* __restrict__ sWx, const float* __restrict__ sWh,
    const float* __restrict__ sWa, const float* __restrict__ sWb, const float* __restrict__ sb,
    const float* __restrict__ dWx, const float* __restrict__ dWh,
    const float* __restrict__ dWa, const float* __restrict__ dWb, const float* __restrict__ db,
    const float* __restrict__ onW, const float* __restrict__ onb,
    const float* __restrict__ osW, const float* __restrict__ osb,
    float* __restrict__ ws)
{
    int* flags = (int*)(ws + OFF_FLAGS);
    float* halo = ws + OFF_HALO;
    float* outs = ws + OFF_OUTS;

    const int tid = threadIdx.x;
    const int blk = blockIdx.x;
    const int r0 = blk * RPB;
    const int b = r0 >> 7;
    const int s0 = r0 & (S_ - 1);
    const bool leftOK = (s0 != 0);
    const bool rightOK = (s0 + RPB != S_);

    __shared__ float sh_hn[RPB + 2][64];   // [0]=left halo, [1..8]=own (persistent), [9]=right halo
    __shared__ float sh_hs[RPB + 2][64];
    __shared__ float sh_hd[RPB + 2][128];
    __shared__ float sh_x[RPB][4];
    __shared__ float sh_hnew[RPB][128];    // dec_in: [0:64)=hn_new, [64:128)=hs_new
    __shared__ float sh_hdnew[RPB][128];
    __shared__ float sh_u[8192];           // 32KB phase-partial union
#define GN_P(kh, r, j) sh_u[(kh) * 2048 + (r) * 256 + (j)]
#define GS_P(kh, r, j) sh_u[4096 + (kh) * 2048 + (r) * 256 + (j)]
#define GD_P(kh, r, j) sh_u[(kh) * 4096 + (r) * 512 + (j)]

    // ---- init persistent state (h in LDS incl. halo slots; c in registers) ----
    for (int i = tid; i < (RPB + 2) * 64; i += TB) { ((float*)sh_hn)[i] = 0.f; ((float*)sh_hs)[i] = 0.f; }
    for (int i = tid; i < (RPB + 2) * 128; i += TB) ((float*)sh_hd)[i] = 0.f;
    float cA = 0.f;   // tid<512: cn(r=tid>>6,k=tid&63); tid>=512: cs(r=(tid-512)>>6,k=...)
    float cD = 0.f;   // cd(r=tid>>7,k=tid&127)

    for (int v = 0; v < NSTEPS; ++v) {
        // ---- neighbor sync + halo ingest (state version v) ----
        if (v > 0) {
            if (tid == 0 && leftOK) {
                while (__hip_atomic_load(&flags[blk - 1], __ATOMIC_ACQUIRE, __HIP_MEMORY_SCOPE_AGENT) < v)
                    __builtin_amdgcn_s_sleep(2);
            }
            if (tid == 64 && rightOK) {
                while (__hip_atomic_load(&flags[blk + 1], __ATOMIC_ACQUIRE, __HIP_MEMORY_SCOPE_AGENT) < v)
                    __builtin_amdgcn_s_sleep(2);
            }
            __syncthreads();
            const int slot = v & 1;
            if (tid < 256) {
                if (leftOK) {
                    const float* src = halo + ((((blk - 1) * 2 + slot) * 2) + 1) * 256;  // left's HIGH side
                    float val = __hip_atomic_load(src + tid, __ATOMIC_RELAXED, __HIP_MEMORY_SCOPE_AGENT);
                    if (tid < 64) sh_hn[0][tid] = val;
                    else if (tid < 128) sh_hs[0][tid - 64] = val;
                    else sh_hd[0][tid - 128] = val;
                }
            } else if (tid < 512) {
                if (rightOK) {
                    int q = tid - 256;
                    const float* src = halo + ((((blk + 1) * 2 + slot) * 2) + 0) * 256;  // right's LOW side
                    float val = __hip_atomic_load(src + q, __ATOMIC_RELAXED, __HIP_MEMORY_SCOPE_AGENT);
                    if (q < 64) sh_hn[RPB + 1][q] = val;
                    else if (q < 128) sh_hs[RPB + 1][q - 64] = val;
                    else sh_hd[RPB + 1][q - 128] = val;
                }
            }
        }
        if (tid < RPB * 4) {
            int rr = tid >> 2, c = tid & 3;
            sh_x[rr][c] = input[(((b * T_) + v) * S_ + (s0 + rr)) * 4 + c];
        }
        __syncthreads();

        const int pslot = (v + 1) & 1;
        float* pubLow = halo + (((blk * 2 + pslot) * 2) + 0) * 256;
        float* pubHigh = halo + (((blk * 2 + pslot) * 2) + 1) * 256;

        // ---- phase A: n/s-cell gate GEMMs. grp 0,1 = n-cell k-halves; 2,3 = s-cell ----
        {
            const int j = tid & 255;
            const int grp = tid >> 8;   // wave-uniform
            float acc[RPB];
            if (grp < 2) {
                const int k0 = grp * 32;
#pragma unroll
                for (int r = 0; r < RPB; ++r)
                    acc[r] = (grp == 0)
                        ? nb[j] + sh_x[r][0] * nWx[j] + sh_x[r][1] * nWx[256 + j] + sh_x[r][2] * nWx[512 + j]
                        : 0.f;
#pragma unroll 4
                for (int k = k0; k < k0 + 32; ++k) {
                    float wh = nWh[k * 256 + j], wa = nWa[k * 256 + j], wb = nWb[k * 256 + j];
#pragma unroll
                    for (int r = 0; r < RPB; ++r)
                        acc[r] += sh_hn[r + 1][k] * wh + sh_hn[r + 2][k] * wa + sh_hn[r][k] * wb;
                }
#pragma unroll
                for (int r = 0; r < RPB; ++r) GN_P(grp, r, j) = acc[r];
            } else {
                const int kh = grp - 2;
                const int k0 = kh * 32;
#pragma unroll
                for (int r = 0; r < RPB; ++r)
                    acc[r] = (kh == 0) ? sb[j] + sh_x[r][3] * sWx[j] : 0.f;
#pragma unroll 4
                for (int k = k0; k < k0 + 32; ++k) {
                    float vh = sWh[k * 256 + j], va = sWa[k * 256 + j], vb = sWb[k * 256 + j];
#pragma unroll
                    for (int r = 0; r < RPB; ++r)
                        acc[r] += sh_hs[r + 1][k] * vh + sh_hs[r + 2][k] * va + sh_hs[r][k] * vb;
                }
#pragma unroll
                for (int r = 0; r < RPB; ++r) GS_P(kh, r, j) = acc[r];
            }
        }
        __syncthreads();

        // ---- epilogue A: gate combine; update persistent LDS h; publish boundary rows ----
        if (tid < 512) {
            int r = tid >> 6, k = tid & 63;
            float gi = GN_P(0, r, k)       + GN_P(1, r, k);
            float gf = GN_P(0, r, 64 + k)  + GN_P(1, r, 64 + k);
            float gu = GN_P(0, r, 128 + k) + GN_P(1, r, 128 + k);
            float go = GN_P(0, r, 192 + k) + GN_P(1, r, 192 + k);
            float c2 = sigm(gf) * cA + sigm(gi) * tanh_(gu);
            float h2 = sigm(go) * tanh_(c2);
            cA = c2; sh_hn[r + 1][k] = h2; sh_hnew[r][k] = h2;
            if (r == 0 && leftOK)
                __hip_atomic_store(pubLow + k, h2, __ATOMIC_RELAXED, __HIP_MEMORY_SCOPE_AGENT);
            if (r == RPB - 1 && rightOK)
                __hip_atomic_store(pubHigh + k, h2, __ATOMIC_RELAXED, __HIP_MEMORY_SCOPE_AGENT);
        } else {
            int t2 = tid - 512;
            int r = t2 >> 6, k = t2 & 63;
            float gi = GS_P(0, r, k)       + GS_P(1, r, k);
            float gf = GS_P(0, r, 64 + k)  + GS_P(1, r, 64 + k);
            float gu = GS_P(0, r, 128 + k) + GS_P(1, r, 128 + k);
            float go = GS_P(0, r, 192 + k) + GS_P(1, r, 192 + k);
            float c2 = sigm(gf) * cA + sigm(gi) * tanh_(gu);
            float h2 = sigm(go) * tanh_(c2);
            cA = c2; sh_hs[r + 1][k] = h2; sh_hnew[r][64 + k] = h2;
            if (r == 0 && leftOK)
                __hip_atomic_store(pubLow + 64 + k, h2, __ATOMIC_RELAXED, __HIP_MEMORY_SCOPE_AGENT);
            if (r == RPB - 1 && rightOK)
                __hip_atomic_store(pubHigh + 64 + k, h2, __ATOMIC_RELAXED, __HIP_MEMORY_SCOPE_AGENT);
        }
        __syncthreads();

        // ---- phase B: d-cell gate GEMM (reads OLD sh_hd + new sh_hnew) ----
        {
            const int j = tid & 511;
            const int kh = tid >> 9;    // wave-uniform
            float acc[RPB];
            if (kh == 0) {
#pragma unroll
                for (int r = 0; r < RPB; ++r) acc[r] = db[j];
#pragma unroll 4
                for (int k = 0; k < 128; ++k) {   // dec_in @ dWx
                    float w = dWx[k * 512 + j];
#pragma unroll
                    for (int r = 0; r < RPB; ++r) acc[r] += sh_hnew[r][k] * w;
                }
#pragma unroll 4
                for (int k = 0; k < 128; ++k) {   // hd @ dWh
                    float w = dWh[k * 512 + j];
#pragma unroll
                    for (int r = 0; r < RPB; ++r) acc[r] += sh_hd[r + 1][k] * w;
                }
            } else {
#pragma unroll
                for (int r = 0; r < RPB; ++r) acc[r] = 0.f;
#pragma unroll 4
                for (int k = 0; k < 128; ++k) {   // hd_a (s+1) @ dWa
                    float w = dWa[k * 512 + j];
#pragma unroll
                    for (int r = 0; r < RPB; ++r) acc[r] += sh_hd[r + 2][k] * w;
                }
#pragma unroll 4
                for (int k = 0; k < 128; ++k) {   // hd_b (s-1) @ dWb
                    float w = dWb[k * 512 + j];
#pragma unroll
                    for (int r = 0; r < RPB; ++r) acc[r] += sh_hd[r][k] * w;
                }
            }
#pragma unroll
            for (int r = 0; r < RPB; ++r) GD_P(kh, r, j) = acc[r];
        }
        __syncthreads();

        // ---- epilogue B: d-cell combine; update persistent hd; publish boundary ----
        {
            int r = tid >> 7, k = tid & 127;
            float gi = GD_P(0, r, k)       + GD_P(1, r, k);
            float gf = GD_P(0, r, 128 + k) + GD_P(1, r, 128 + k);
            float gu = GD_P(0, r, 256 + k) + GD_P(1, r, 256 + k);
            float go = GD_P(0, r, 384 + k) + GD_P(1, r, 384 + k);
            float c2 = sigm(gf) * cD + sigm(gi) * tanh_(gu);
            float h2 = sigm(go) * tanh_(c2);
            cD = c2; sh_hd[r + 1][k] = h2; sh_hdnew[r][k] = h2;
            if (r == 0 && leftOK)
                __hip_atomic_store(pubLow + 128 + k, h2, __ATOMIC_RELAXED, __HIP_MEMORY_SCOPE_AGENT);
            if (r == RPB - 1 && rightOK)
                __hip_atomic_store(pubHigh + 128 + k, h2, __ATOMIC_RELAXED, __HIP_MEMORY_SCOPE_AGENT);
        }
        __syncthreads();

        // ---- output heads: one wave per (row, head); store to global outs ----
        {
            int p = tid >> 6, l = tid & 63;    // p in [0,16)
            int r = p >> 1, head = p & 1;
            const float* W = head ? osW : onW;
            float partial = sh_hdnew[r][l] * W[l] + sh_hdnew[r][64 + l] * W[64 + l];
#pragma unroll
            for (int off = 32; off; off >>= 1) partial += __shfl_down(partial, off);
            if (l == 0) outs[(v * ROWS + (r0 + r)) * 2 + head] = partial + (head ? osb[0] : onb[0]);
        }

        // ---- make publishes visible, then bump flag ----
        __threadfence();
        __syncthreads();
        if (tid == 0)
            __hip_atomic_store(&flags[blk], v + 1, __ATOMIC_RELEASE, __HIP_MEMORY_SCOPE_AGENT);
    }
#undef GN_P
#undef GS_P
#undef GD_P
}

// Assemble data outputs for t in [20,126] from stored head outputs.
__global__ __launch_bounds__(256) void assemble_kernel(
    const float* __restrict__ input, const float* __restrict__ ws, float* __restrict__ out)
{
    const float* outs = ws + OFF_OUTS;
    int idx = blockIdx.x * 256 + threadIdx.x;  // (b, tt, s)
    if (idx >= B_ * TOUT * S_) return;
    int s = idx & 127;
    int tmp = idx >> 7;
    int tt = tmp % TOUT;
    int b = tmp / TOUT;
    int t = tt + TPRED;
    int row = b * S_ + s;
    float o0 = outs[(t * ROWS + row) * 2 + 0];
    float o1 = outs[(t * ROWS + row) * 2 + 1];
    float inflow = (s == 0) ? input[(((b * T_) + (t + 1)) * S_ + 0) * 4 + 1]
                            : outs[(t * ROWS + row - 1) * 2 + 0];
    float numc = input[(((b * T_) + t) * S_ + s) * 4 + 2] + inflow - o0;
    float spd = (s == 0) ? input[(((b * T_) + (t + 1)) * S_ + 0) * 4 + 3] : o1;
    float4 v = make_float4(o0, inflow, numc, spd);
    reinterpret_cast<float4*>(out)[idx] = v;
}

extern "C" void kernel_launch(void* const* d_in, const int* in_sizes, int n_in,
                              void* d_out, int out_size, void* d_ws, size_t ws_size,
                              hipStream_t stream) {
    const float* input = (const float*)d_in[0];
    const float* nWx = (const float*)d_in[1];
    const float* nWh = (const float*)d_in[2];
    const float* nWa = (const float*)d_in[3];
    const float* nWb = (const float*)d_in[4];
    const float* nb  = (const float*)d_in[5];
    const float* sWx = (const float*)d_in[6];
    const float* sWh = (const float*)d_in[7];
    const float* sWa = (const float*)d_in[8];
    const float* sWb = (const float*)d_in[9];
    const float* sb  = (const float*)d_in[10];
    const float* dWx = (const float*)d_in[11];
    const float* dWh = (const float*)d_in[12];
    const float* dWa = (const float*)d_in[13];
    const float* dWb = (const float*)d_in[14];
    const float* db  = (const float*)d_in[15];
    const float* onW = (const float*)d_in[16];
    const float* onb = (const float*)d_in[17];
    const float* osW = (const float*)d_in[18];
    const float* osb = (const float*)d_in[19];

    float* ws = (float*)d_ws;

    // zero flags + halo region (ws is poisoned 0xAA before every call)
    hipMemsetAsync(ws, 0, (size_t)ZERO_FLOATS * sizeof(float), stream);

    void* args[] = {
        (void*)&input,
        (void*)&nWx, (void*)&nWh, (void*)&nWa, (void*)&nWb, (void*)&nb,
        (void*)&sWx, (void*)&sWh, (void*)&sWa, (void*)&sWb, (void*)&sb,
        (void*)&dWx, (void*)&dWh, (void*)&dWa, (void*)&dWb, (void*)&db,
        (void*)&onW, (void*)&onb, (void*)&osW, (void*)&osb,
        (void*)&ws,
    };
    hipLaunchCooperativeKernel((const void*)persist_kernel,
                               dim3(NBLK), dim3(TB), args, 0, stream);

    int nout = B_ * TOUT * S_;
    assemble_kernel<<<dim3((nout + 255) / 256), dim3(256), 0, stream>>>(input, ws, (float*)d_out);
}

// Round 4
// 4539.797 us; speedup vs baseline: 2.9717x; 2.9717x over previous
//
#include <hip/hip_runtime.h>

// Problem constants (from reference)
constexpr int B_ = 16, T_ = 128, S_ = 128;
constexpr int ROWS = B_ * S_;        // 2048
constexpr int NSTEPS = T_ - 1;       // 127
constexpr int TPRED = 20;
constexpr int TOUT = NSTEPS - TPRED; // 107
constexpr int RPB = 4;               // rows per block (4 | 128: blocks never straddle a batch)
constexpr int TB = 512;              // 8 waves/block; grid=512 -> 2 blocks/CU = 16 waves/CU
constexpr int NBLK = ROWS / RPB;     // 512 blocks

// ws layout (floats)
constexpr int OFF_HN = 0;
constexpr int OFF_HS = OFF_HN + 2 * ROWS * 64;
constexpr int OFF_HD = OFF_HS + 2 * ROWS * 64;
constexpr int OFF_CN = OFF_HD + 2 * ROWS * 128;
constexpr int OFF_CS = OFF_CN + ROWS * 64;
constexpr int OFF_CD = OFF_CS + ROWS * 64;
constexpr int OFF_OUTS = OFF_CD + ROWS * 128;
constexpr int STATE_FLOATS = OFF_OUTS;

__device__ __forceinline__ float sigm(float x) { return 1.f / (1.f + __expf(-x)); }
__device__ __forceinline__ float tanh_(float x) { return 2.f / (1.f + __expf(-2.f * x)) - 1.f; }
// wave-uniform broadcast from register lane k -> SGPR (h[r][k] is uniform per wave)
__device__ __forceinline__ float rdlane(float v, int l) {
    return __int_as_float(__builtin_amdgcn_readlane(__float_as_int(v), l));
}

__global__ __launch_bounds__(TB, 4) void step_kernel(
    int t,
    const float* __restrict__ input,
    const float* __restrict__ nWx, const float* __restrict__ nWh,
    const float* __restrict__ nWa, const float* __restrict__ nWb, const float* __restrict__ nb,
    const float* __restrict__ sWx, const float* __restrict__ sWh,
    const float* __restrict__ sWa, const float* __restrict__ sWb, const float* __restrict__ sb,
    const float* __restrict__ dWx, const float* __restrict__ dWh,
    const float* __restrict__ dWa, const float* __restrict__ dWb, const float* __restrict__ db,
    const float* __restrict__ onW, const float* __restrict__ onb,
    const float* __restrict__ osW, const float* __restrict__ osb,
    float* __restrict__ ws)
{
    float* hnBuf = ws + OFF_HN;
    float* hsBuf = ws + OFF_HS;
    float* hdBuf = ws + OFF_HD;
    float* cn = ws + OFF_CN;
    float* cs = ws + OFF_CS;
    float* cd = ws + OFF_CD;
    float* outs = ws + OFF_OUTS;

    const int cur = t & 1, nxt = cur ^ 1;
    const float* hnC = hnBuf + cur * ROWS * 64;
    const float* hsC = hsBuf + cur * ROWS * 64;
    const float* hdC = hdBuf + cur * ROWS * 128;
    float* hnN = hnBuf + nxt * ROWS * 64;
    float* hsN = hsBuf + nxt * ROWS * 64;
    float* hdN = hdBuf + nxt * ROWS * 128;

    const int tid = threadIdx.x;
    const int lane = tid & 63;
    const int r0 = blockIdx.x * RPB;
    const int b = r0 >> 7;
    const int s0 = r0 & (S_ - 1);
    const bool leftOK = (s0 != 0);
    const bool rightOK = (s0 + RPB != S_);

    __shared__ float sh_hn[RPB + 2][64];   // [0]=left halo, [1..4]=own, [5]=right halo
    __shared__ float sh_hs[RPB + 2][64];
    __shared__ float sh_hd[RPB + 2][128];
    __shared__ float sh_x[RPB][4];
    __shared__ float sh_hnew[RPB][128];    // dec_in: [0:64)=hn_new, [64:128)=hs_new
    __shared__ float sh_hdnew[RPB][128];
    // 32KB union: A: gn2[2][4][256] (8KB) + gs2[2][4][256] (8KB); B: gd4[4][4][512] (32KB)
    __shared__ float sh_u[8192];
#define GN2(kh, r, j) sh_u[(kh) * 1024 + (r) * 256 + (j)]
#define GS2(kh, r, j) sh_u[2048 + (kh) * 1024 + (r) * 256 + (j)]
#define GD4(q, r, j)  sh_u[(q) * 2048 + (r) * 512 + (j)]

    // ---- stage old h states (+halo) and x into LDS ----
    if (tid < (RPB + 2) * 64) {
        int rr = tid >> 6, k = tid & 63;
        int row = r0 + rr - 1;
        bool v = (rr == 0) ? leftOK : ((rr == RPB + 1) ? rightOK : true);
        sh_hn[rr][k] = v ? hnC[row * 64 + k] : 0.f;
        sh_hs[rr][k] = v ? hsC[row * 64 + k] : 0.f;
    }
    for (int i = tid; i < (RPB + 2) * 128; i += TB) {
        int rr = i >> 7, k = i & 127;
        int row = r0 + rr - 1;
        bool v = (rr == 0) ? leftOK : ((rr == RPB + 1) ? rightOK : true);
        sh_hd[rr][k] = v ? hdC[row * 128 + k] : 0.f;
    }
    if (tid < RPB * 4) {
        int rr = tid >> 2, c = tid & 3;
        sh_x[rr][c] = input[(((b * T_) + t) * S_ + (s0 + rr)) * 4 + c];
    }
    __syncthreads();

    // ---- phase A: n/s-cell gate GEMMs ----
    // tid -> cell = tid>>8 (0=n,1=s); u=tid&255: cp=u&127 (cols 2cp,2cp+1), kh=u>>7 (k half)
    {
        const int cell = tid >> 8;
        const int u = tid & 255;
        const int cp = u & 127;
        const int kh = u >> 7;
        const int c0 = 2 * cp;
        const int k0 = kh * 32;
        float h0, h1, h2, h3, h4, h5;
        const float *Wh, *Wa, *Wb;
        float a00, a01, a10, a11, a20, a21, a30, a31;
        if (cell == 0) {
            h0 = sh_hn[0][lane]; h1 = sh_hn[1][lane]; h2 = sh_hn[2][lane];
            h3 = sh_hn[3][lane]; h4 = sh_hn[4][lane]; h5 = sh_hn[5][lane];
            Wh = nWh; Wa = nWa; Wb = nWb;
            if (kh == 0) {
                float b0 = nb[c0], b1 = nb[c0 + 1];
                float w00 = nWx[c0], w01 = nWx[c0 + 1];
                float w10 = nWx[256 + c0], w11 = nWx[256 + c0 + 1];
                float w20 = nWx[512 + c0], w21 = nWx[512 + c0 + 1];
                a00 = b0 + sh_x[0][0] * w00 + sh_x[0][1] * w10 + sh_x[0][2] * w20;
                a01 = b1 + sh_x[0][0] * w01 + sh_x[0][1] * w11 + sh_x[0][2] * w21;
                a10 = b0 + sh_x[1][0] * w00 + sh_x[1][1] * w10 + sh_x[1][2] * w20;
                a11 = b1 + sh_x[1][0] * w01 + sh_x[1][1] * w11 + sh_x[1][2] * w21;
                a20 = b0 + sh_x[2][0] * w00 + sh_x[2][1] * w10 + sh_x[2][2] * w20;
                a21 = b1 + sh_x[2][0] * w01 + sh_x[2][1] * w11 + sh_x[2][2] * w21;
                a30 = b0 + sh_x[3][0] * w00 + sh_x[3][1] * w10 + sh_x[3][2] * w20;
                a31 = b1 + sh_x[3][0] * w01 + sh_x[3][1] * w11 + sh_x[3][2] * w21;
            } else {
                a00 = a01 = a10 = a11 = a20 = a21 = a30 = a31 = 0.f;
            }
        } else {
            h0 = sh_hs[0][lane]; h1 = sh_hs[1][lane]; h2 = sh_hs[2][lane];
            h3 = sh_hs[3][lane]; h4 = sh_hs[4][lane]; h5 = sh_hs[5][lane];
            Wh = sWh; Wa = sWa; Wb = sWb;
            if (kh == 0) {
                float b0 = sb[c0], b1 = sb[c0 + 1];
                float w00 = sWx[c0], w01 = sWx[c0 + 1];
                a00 = b0 + sh_x[0][3] * w00; a01 = b1 + sh_x[0][3] * w01;
                a10 = b0 + sh_x[1][3] * w00; a11 = b1 + sh_x[1][3] * w01;
                a20 = b0 + sh_x[2][3] * w00; a21 = b1 + sh_x[2][3] * w01;
                a30 = b0 + sh_x[3][3] * w00; a31 = b1 + sh_x[3][3] * w01;
            } else {
                a00 = a01 = a10 = a11 = a20 = a21 = a30 = a31 = 0.f;
            }
        }
#pragma unroll 8
        for (int k = k0; k < k0 + 32; ++k) {
            float2 wh = *(const float2*)(Wh + k * 256 + c0);
            float2 wa = *(const float2*)(Wa + k * 256 + c0);
            float2 wb = *(const float2*)(Wb + k * 256 + c0);
            float v0 = rdlane(h0, k), v1 = rdlane(h1, k), v2 = rdlane(h2, k);
            float v3 = rdlane(h3, k), v4 = rdlane(h4, k), v5 = rdlane(h5, k);
            a00 += v1 * wh.x + v2 * wa.x + v0 * wb.x;
            a01 += v1 * wh.y + v2 * wa.y + v0 * wb.y;
            a10 += v2 * wh.x + v3 * wa.x + v1 * wb.x;
            a11 += v2 * wh.y + v3 * wa.y + v1 * wb.y;
            a20 += v3 * wh.x + v4 * wa.x + v2 * wb.x;
            a21 += v3 * wh.y + v4 * wa.y + v2 * wb.y;
            a30 += v4 * wh.x + v5 * wa.x + v3 * wb.x;
            a31 += v4 * wh.y + v5 * wa.y + v3 * wb.y;
        }
        if (cell == 0) {
            GN2(kh, 0, c0) = a00; GN2(kh, 0, c0 + 1) = a01;
            GN2(kh, 1, c0) = a10; GN2(kh, 1, c0 + 1) = a11;
            GN2(kh, 2, c0) = a20; GN2(kh, 2, c0 + 1) = a21;
            GN2(kh, 3, c0) = a30; GN2(kh, 3, c0 + 1) = a31;
        } else {
            GS2(kh, 0, c0) = a00; GS2(kh, 0, c0 + 1) = a01;
            GS2(kh, 1, c0) = a10; GS2(kh, 1, c0 + 1) = a11;
            GS2(kh, 2, c0) = a20; GS2(kh, 2, c0 + 1) = a21;
            GS2(kh, 3, c0) = a30; GS2(kh, 3, c0 + 1) = a31;
        }
    }
    __syncthreads();

    // ---- epilogue A: gate combine, n-cell (tid<256) / s-cell (tid>=256) ----
    if (tid < 256) {
        int r = tid >> 6, k = tid & 63;
        int row = r0 + r;
        float gi = GN2(0, r, k)       + GN2(1, r, k);
        float gf = GN2(0, r, 64 + k)  + GN2(1, r, 64 + k);
        float gu = GN2(0, r, 128 + k) + GN2(1, r, 128 + k);
        float go = GN2(0, r, 192 + k) + GN2(1, r, 192 + k);
        float c2 = sigm(gf) * cn[row * 64 + k] + sigm(gi) * tanh_(gu);
        float h2 = sigm(go) * tanh_(c2);
        cn[row * 64 + k] = c2; hnN[row * 64 + k] = h2; sh_hnew[r][k] = h2;
    } else {
        int t2 = tid - 256;
        int r = t2 >> 6, k = t2 & 63;
        int row = r0 + r;
        float gi = GS2(0, r, k)       + GS2(1, r, k);
        float gf = GS2(0, r, 64 + k)  + GS2(1, r, 64 + k);
        float gu = GS2(0, r, 128 + k) + GS2(1, r, 128 + k);
        float go = GS2(0, r, 192 + k) + GS2(1, r, 192 + k);
        float c2 = sigm(gf) * cs[row * 64 + k] + sigm(gi) * tanh_(gu);
        float h2 = sigm(go) * tanh_(c2);
        cs[row * 64 + k] = c2; hsN[row * 64 + k] = h2; sh_hnew[r][64 + k] = h2;
    }
    __syncthreads();

    // ---- phase B: d-cell gate GEMM. tid -> q=tid>>7 (matrix: Wx,Wh,Wa,Wb), cq=tid&127 (cols 4cq..) ----
    {
        const int q = tid >> 7;
        const int cq = tid & 127;
        const int c0 = 4 * cq;
        const float* W;
        float pa0, pa1, pa2, pa3;   // chunk 0 (k=0..63) h regs, rows 0..3 of the q-specific view
        float pb0, pb1, pb2, pb3;   // chunk 1 (k=64..127)
        if (q == 0) {
            W = dWx;
            pa0 = sh_hnew[0][lane]; pa1 = sh_hnew[1][lane]; pa2 = sh_hnew[2][lane]; pa3 = sh_hnew[3][lane];
            pb0 = sh_hnew[0][64 + lane]; pb1 = sh_hnew[1][64 + lane]; pb2 = sh_hnew[2][64 + lane]; pb3 = sh_hnew[3][64 + lane];
        } else if (q == 1) {
            W = dWh;
            pa0 = sh_hd[1][lane]; pa1 = sh_hd[2][lane]; pa2 = sh_hd[3][lane]; pa3 = sh_hd[4][lane];
            pb0 = sh_hd[1][64 + lane]; pb1 = sh_hd[2][64 + lane]; pb2 = sh_hd[3][64 + lane]; pb3 = sh_hd[4][64 + lane];
        } else if (q == 2) {
            W = dWa;
            pa0 = sh_hd[2][lane]; pa1 = sh_hd[3][lane]; pa2 = sh_hd[4][lane]; pa3 = sh_hd[5][lane];
            pb0 = sh_hd[2][64 + lane]; pb1 = sh_hd[3][64 + lane]; pb2 = sh_hd[4][64 + lane]; pb3 = sh_hd[5][64 + lane];
        } else {
            W = dWb;
            pa0 = sh_hd[0][lane]; pa1 = sh_hd[1][lane]; pa2 = sh_hd[2][lane]; pa3 = sh_hd[3][lane];
            pb0 = sh_hd[0][64 + lane]; pb1 = sh_hd[1][64 + lane]; pb2 = sh_hd[2][64 + lane]; pb3 = sh_hd[3][64 + lane];
        }
        float acc[4][4];
#pragma unroll
        for (int r = 0; r < 4; ++r)
#pragma unroll
            for (int i = 0; i < 4; ++i)
                acc[r][i] = (q == 0) ? db[c0 + i] : 0.f;

#pragma unroll 8
        for (int k = 0; k < 64; ++k) {
            float4 w = *(const float4*)(W + k * 512 + c0);
            float v0 = rdlane(pa0, k), v1 = rdlane(pa1, k), v2 = rdlane(pa2, k), v3 = rdlane(pa3, k);
            acc[0][0] += v0 * w.x; acc[0][1] += v0 * w.y; acc[0][2] += v0 * w.z; acc[0][3] += v0 * w.w;
            acc[1][0] += v1 * w.x; acc[1][1] += v1 * w.y; acc[1][2] += v1 * w.z; acc[1][3] += v1 * w.w;
            acc[2][0] += v2 * w.x; acc[2][1] += v2 * w.y; acc[2][2] += v2 * w.z; acc[2][3] += v2 * w.w;
            acc[3][0] += v3 * w.x; acc[3][1] += v3 * w.y; acc[3][2] += v3 * w.z; acc[3][3] += v3 * w.w;
        }
#pragma unroll 8
        for (int k = 0; k < 64; ++k) {
            float4 w = *(const float4*)(W + (64 + k) * 512 + c0);
            float v0 = rdlane(pb0, k), v1 = rdlane(pb1, k), v2 = rdlane(pb2, k), v3 = rdlane(pb3, k);
            acc[0][0] += v0 * w.x; acc[0][1] += v0 * w.y; acc[0][2] += v0 * w.z; acc[0][3] += v0 * w.w;
            acc[1][0] += v1 * w.x; acc[1][1] += v1 * w.y; acc[1][2] += v1 * w.z; acc[1][3] += v1 * w.w;
            acc[2][0] += v2 * w.x; acc[2][1] += v2 * w.y; acc[2][2] += v2 * w.z; acc[2][3] += v2 * w.w;
            acc[3][0] += v3 * w.x; acc[3][1] += v3 * w.y; acc[3][2] += v3 * w.z; acc[3][3] += v3 * w.w;
        }
#pragma unroll
        for (int r = 0; r < 4; ++r)
#pragma unroll
            for (int i = 0; i < 4; ++i)
                GD4(q, r, c0 + i) = acc[r][i];
    }
    __syncthreads();

    // ---- epilogue B: d-cell gate combine (512 items = 4 rows x 128) ----
    {
        int r = tid >> 7, k = tid & 127;
        int row = r0 + r;
        float gi = GD4(0, r, k)       + GD4(1, r, k)       + GD4(2, r, k)       + GD4(3, r, k);
        float gf = GD4(0, r, 128 + k) + GD4(1, r, 128 + k) + GD4(2, r, 128 + k) + GD4(3, r, 128 + k);
        float gu = GD4(0, r, 256 + k) + GD4(1, r, 256 + k) + GD4(2, r, 256 + k) + GD4(3, r, 256 + k);
        float go = GD4(0, r, 384 + k) + GD4(1, r, 384 + k) + GD4(2, r, 384 + k) + GD4(3, r, 384 + k);
        float c2 = sigm(gf) * cd[row * 128 + k] + sigm(gi) * tanh_(gu);
        float h2 = sigm(go) * tanh_(c2);
        cd[row * 128 + k] = c2; hdN[row * 128 + k] = h2; sh_hdnew[r][k] = h2;
    }
    __syncthreads();

    // ---- output heads: one wave per (row, head) ----
    {
        int p = tid >> 6;              // 0..7
        int r = p >> 1, head = p & 1;
        const float* W = head ? osW : onW;
        float partial = sh_hdnew[r][lane] * W[lane] + sh_hdnew[r][64 + lane] * W[64 + lane];
#pragma unroll
        for (int off = 32; off; off >>= 1) partial += __shfl_down(partial, off);
        if (lane == 0) outs[(t * ROWS + (r0 + r)) * 2 + head] = partial + (head ? osb[0] : onb[0]);
    }
#undef GN2
#undef GS2
#undef GD4
}

// Assemble data outputs for t in [20,126] from stored head outputs.
__global__ __launch_bounds__(256) void assemble_kernel(
    const float* __restrict__ input, const float* __restrict__ ws, float* __restrict__ out)
{
    const float* outs = ws + OFF_OUTS;
    int idx = blockIdx.x * 256 + threadIdx.x;  // (b, tt, s)
    if (idx >= B_ * TOUT * S_) return;
    int s = idx & 127;
    int tmp = idx >> 7;
    int tt = tmp % TOUT;
    int b = tmp / TOUT;
    int t = tt + TPRED;
    int row = b * S_ + s;
    float o0 = outs[(t * ROWS + row) * 2 + 0];
    float o1 = outs[(t * ROWS + row) * 2 + 1];
    float inflow = (s == 0) ? input[(((b * T_) + (t + 1)) * S_ + 0) * 4 + 1]
                            : outs[(t * ROWS + row - 1) * 2 + 0];
    float numc = input[(((b * T_) + t) * S_ + s) * 4 + 2] + inflow - o0;
    float spd = (s == 0) ? input[(((b * T_) + (t + 1)) * S_ + 0) * 4 + 3] : o1;
    float4 v = make_float4(o0, inflow, numc, spd);
    reinterpret_cast<float4*>(out)[idx] = v;
}

extern "C" void kernel_launch(void* const* d_in, const int* in_sizes, int n_in,
                              void* d_out, int out_size, void* d_ws, size_t ws_size,
                              hipStream_t stream) {
    const float* input = (const float*)d_in[0];
    const float* nWx = (const float*)d_in[1];
    const float* nWh = (const float*)d_in[2];
    const float* nWa = (const float*)d_in[3];
    const float* nWb = (const float*)d_in[4];
    const float* nb  = (const float*)d_in[5];
    const float* sWx = (const float*)d_in[6];
    const float* sWh = (const float*)d_in[7];
    const float* sWa = (const float*)d_in[8];
    const float* sWb = (const float*)d_in[9];
    const float* sb  = (const float*)d_in[10];
    const float* dWx = (const float*)d_in[11];
    const float* dWh = (const float*)d_in[12];
    const float* dWa = (const float*)d_in[13];
    const float* dWb = (const float*)d_in[14];
    const float* db  = (const float*)d_in[15];
    const float* onW = (const float*)d_in[16];
    const float* onb = (const float*)d_in[17];
    const float* osW = (const float*)d_in[18];
    const float* osb = (const float*)d_in[19];

    float* ws = (float*)d_ws;

    // zero the recurrent state region (ws is poisoned 0xAA before every call)
    hipMemsetAsync(ws, 0, (size_t)STATE_FLOATS * sizeof(float), stream);

    for (int t = 0; t < NSTEPS; ++t) {
        step_kernel<<<dim3(NBLK), dim3(TB), 0, stream>>>(
            t, input,
            nWx, nWh, nWa, nWb, nb,
            sWx, sWh, sWa, sWb, sb,
            dWx, dWh, dWa, dWb, db,
            onW, onb, osW, osb, ws);
    }

    int nout = B_ * TOUT * S_;
    assemble_kernel<<<dim3((nout + 255) / 256), dim3(256), 0, stream>>>(input, ws, (float*)d_out);
}

// Round 5
// 3552.486 us; speedup vs baseline: 3.7976x; 1.2779x over previous
//
#include <hip/hip_runtime.h>

// Problem constants (from reference)
constexpr int B_ = 16, T_ = 128, S_ = 128;
constexpr int ROWS = B_ * S_;        // 2048
constexpr int NSTEPS = T_ - 1;       // 127
constexpr int TPRED = 20;
constexpr int TOUT = NSTEPS - TPRED; // 107
constexpr int RPB = 8;               // rows per block (blocks never straddle a batch)
constexpr int TB = 1024;             // 16 waves/CU at grid=256 (1 block/CU)
constexpr int NBLK = ROWS / RPB;     // 256

// ws layout (floats / 4B units)
constexpr int OFF_HN = 0;                          // [2][2048][64]
constexpr int OFF_HS = OFF_HN + 2 * ROWS * 64;
constexpr int OFF_HD = OFF_HS + 2 * ROWS * 64;     // [2][2048][128]
constexpr int OFF_CN = OFF_HD + 2 * ROWS * 128;
constexpr int OFF_CS = OFF_CN + ROWS * 64;
constexpr int OFF_CD = OFF_CS + ROWS * 64;
constexpr int OFF_OUTS = OFF_CD + ROWS * 128;      // [127][2048][2]
constexpr int STATE_FLOATS = OFF_OUTS;             // zero region (h,c)
// packed fp16 weights (uints): npk[3][32][256], spk[3][32][256], dpk[4][64][512]
constexpr int OFF_NPK = OFF_OUTS + NSTEPS * ROWS * 2;
constexpr int NPK_SZ = 3 * 32 * 256;               // 24576
constexpr int OFF_SPK = OFF_NPK + NPK_SZ;
constexpr int OFF_DPK = OFF_SPK + NPK_SZ;
constexpr int DPK_SZ = 4 * 64 * 512;               // 131072
constexpr int PACK_TOTAL = 2 * NPK_SZ + DPK_SZ;    // 180224

typedef _Float16 half2_t __attribute__((ext_vector_type(2)));

__device__ __forceinline__ float sigm(float x) { return 1.f / (1.f + __expf(-x)); }
__device__ __forceinline__ float tanh_(float x) { return 2.f / (1.f + __expf(-2.f * x)) - 1.f; }
__device__ __forceinline__ half2_t u2h(unsigned int u) {
    union { unsigned int u; half2_t h; } x; x.u = u; return x.h;
}
__device__ __forceinline__ unsigned int pack2(float a, float b) {
    union { unsigned int u; half2_t h; } x;
    x.h = half2_t{(_Float16)a, (_Float16)b}; return x.u;
}
__device__ __forceinline__ half2_t rdl_h2(int v, int l) {
    return u2h((unsigned int)__builtin_amdgcn_readlane(v, l));
}

// ---- pack fp32 weight matrices into [kk][col] half2-pair dwords ----
__global__ __launch_bounds__(256) void pack_weights(
    const float* __restrict__ nWh, const float* __restrict__ nWa, const float* __restrict__ nWb,
    const float* __restrict__ sWh, const float* __restrict__ sWa, const float* __restrict__ sWb,
    const float* __restrict__ dWx, const float* __restrict__ dWh,
    const float* __restrict__ dWa, const float* __restrict__ dWb,
    unsigned int* __restrict__ wsu)
{
    int idx = blockIdx.x * 256 + threadIdx.x;
    if (idx >= PACK_TOTAL) return;
    if (idx < NPK_SZ) {
        int m = idx >> 13, rem = idx & 8191, kk = rem >> 8, c = rem & 255;
        const float* W = (m == 0) ? nWh : (m == 1) ? nWa : nWb;
        wsu[OFF_NPK + idx] = pack2(W[(2 * kk) * 256 + c], W[(2 * kk + 1) * 256 + c]);
    } else if (idx < 2 * NPK_SZ) {
        int j = idx - NPK_SZ;
        int m = j >> 13, rem = j & 8191, kk = rem >> 8, c = rem & 255;
        const float* W = (m == 0) ? sWh : (m == 1) ? sWa : sWb;
        wsu[OFF_SPK + j] = pack2(W[(2 * kk) * 256 + c], W[(2 * kk + 1) * 256 + c]);
    } else {
        int j = idx - 2 * NPK_SZ;
        int m = j >> 15, rem = j & 32767, kk = rem >> 9, c = rem & 511;
        const float* W = (m == 0) ? dWx : (m == 1) ? dWh : (m == 2) ? dWa : dWb;
        wsu[OFF_DPK + j] = pack2(W[(2 * kk) * 512 + c], W[(2 * kk + 1) * 512 + c]);
    }
}

__global__ __launch_bounds__(TB, 4) void step_kernel(
    int t,
    const float* __restrict__ input,
    const float* __restrict__ nWx, const float* __restrict__ nb,
    const float* __restrict__ sWx, const float* __restrict__ sb,
    const float* __restrict__ db,
    const float* __restrict__ onW, const float* __restrict__ onb,
    const float* __restrict__ osW, const float* __restrict__ osb,
    float* __restrict__ ws)
{
    float* hnBuf = ws + OFF_HN;
    float* hsBuf = ws + OFF_HS;
    float* hdBuf = ws + OFF_HD;
    float* cn = ws + OFF_CN;
    float* cs = ws + OFF_CS;
    float* cd = ws + OFF_CD;
    float* outs = ws + OFF_OUTS;
    const unsigned int* npk = (const unsigned int*)ws + OFF_NPK;
    const unsigned int* spk = (const unsigned int*)ws + OFF_SPK;
    const unsigned int* dpk = (const unsigned int*)ws + OFF_DPK;

    const int cur = t & 1, nxt = cur ^ 1;
    const float* hnC = hnBuf + cur * ROWS * 64;
    const float* hsC = hsBuf + cur * ROWS * 64;
    const float* hdC = hdBuf + cur * ROWS * 128;
    float* hnN = hnBuf + nxt * ROWS * 64;
    float* hsN = hsBuf + nxt * ROWS * 64;
    float* hdN = hdBuf + nxt * ROWS * 128;

    const int tid = threadIdx.x;
    const int lane = tid & 63;
    const int r0 = blockIdx.x * RPB;
    const int b = r0 >> 7;
    const int s0 = r0 & (S_ - 1);
    const bool leftOK = (s0 != 0);
    const bool rightOK = (s0 + RPB != S_);

    // packed (half2) old h states, rows -1..8 (10 rows)
    __shared__ unsigned int sh_hnp[10][32];
    __shared__ unsigned int sh_hsp[10][32];
    __shared__ unsigned int sh_hdp[10][64];
    __shared__ unsigned int sh_hnewp[8][64];  // packed dec_in: [0:32)=hn pairs, [32:64)=hs pairs
    __shared__ float sh_hdnew[8][128];        // fp32 for heads
    __shared__ float sh_x[8][4];
    // partial-sum union: phase A gn[2][8][256] + gs[2][8][256] (32KB); phase B gd[4][8][512] (64KB)
    __shared__ float sh_u[16384];
#define GN(kh, r, c) sh_u[(kh) * 2048 + (r) * 256 + (c)]
#define GS(kh, r, c) sh_u[8192 + (kh) * 2048 + (r) * 256 + (c)]
#define GD(q, r, c)  sh_u[(q) * 4096 + (r) * 512 + (c)]

    // ---- stage old h (+halo) packed to fp16 pairs; x fp32 ----
    for (int i = tid; i < 1312; i += TB) {
        if (i < 320) {
            int rr = i >> 5, p = i & 31;
            int row = r0 + rr - 1;
            bool v = (rr == 0) ? leftOK : ((rr == 9) ? rightOK : true);
            float2 h = v ? *(const float2*)(hnC + row * 64 + 2 * p) : float2{0.f, 0.f};
            sh_hnp[rr][p] = pack2(h.x, h.y);
        } else if (i < 640) {
            int j = i - 320;
            int rr = j >> 5, p = j & 31;
            int row = r0 + rr - 1;
            bool v = (rr == 0) ? leftOK : ((rr == 9) ? rightOK : true);
            float2 h = v ? *(const float2*)(hsC + row * 64 + 2 * p) : float2{0.f, 0.f};
            sh_hsp[rr][p] = pack2(h.x, h.y);
        } else if (i < 1280) {
            int j = i - 640;
            int rr = j >> 6, p = j & 63;
            int row = r0 + rr - 1;
            bool v = (rr == 0) ? leftOK : ((rr == 9) ? rightOK : true);
            float2 h = v ? *(const float2*)(hdC + row * 128 + 2 * p) : float2{0.f, 0.f};
            sh_hdp[rr][p] = pack2(h.x, h.y);
        } else {
            int j = i - 1280;
            int rr = j >> 2, ch = j & 3;
            sh_x[rr][ch] = input[(((b * T_) + t) * S_ + (s0 + rr)) * 4 + ch];
        }
    }
    __syncthreads();

    // ---- phase A: n/s gate GEMMs via dot2. cell=tid>>9; col=tid&255; kh=(tid>>8)&1 ----
    {
        const int cell = tid >> 9;
        const int col = tid & 255;
        const int kh = (tid >> 8) & 1;
        int hp[10];
        if (cell == 0) {
#pragma unroll
            for (int rr = 0; rr < 10; ++rr) hp[rr] = (int)sh_hnp[rr][lane & 31];
        } else {
#pragma unroll
            for (int rr = 0; rr < 10; ++rr) hp[rr] = (int)sh_hsp[rr][lane & 31];
        }
        float acc[8];
        if (kh == 0) {
            if (cell == 0) {
                float bb = nb[col];
                float w0 = nWx[col], w1 = nWx[256 + col], w2 = nWx[512 + col];
#pragma unroll
                for (int r = 0; r < 8; ++r)
                    acc[r] = bb + sh_x[r][0] * w0 + sh_x[r][1] * w1 + sh_x[r][2] * w2;
            } else {
                float bb = sb[col], w0 = sWx[col];
#pragma unroll
                for (int r = 0; r < 8; ++r) acc[r] = bb + sh_x[r][3] * w0;
            }
        } else {
#pragma unroll
            for (int r = 0; r < 8; ++r) acc[r] = 0.f;
        }
        const unsigned int* PK = (cell == 0) ? npk : spk;
        const int kk0 = kh * 16;
#pragma unroll 4
        for (int kk = kk0; kk < kk0 + 16; ++kk) {
            half2_t wh = u2h(PK[kk * 256 + col]);
            half2_t wa = u2h(PK[8192 + kk * 256 + col]);
            half2_t wb = u2h(PK[16384 + kk * 256 + col]);
            half2_t hv[10];
#pragma unroll
            for (int rr = 0; rr < 10; ++rr) hv[rr] = rdl_h2(hp[rr], kk);
#pragma unroll
            for (int r = 0; r < 8; ++r) {
                acc[r] = __builtin_amdgcn_fdot2(hv[r + 1], wh, acc[r], false);
                acc[r] = __builtin_amdgcn_fdot2(hv[r + 2], wa, acc[r], false);
                acc[r] = __builtin_amdgcn_fdot2(hv[r],     wb, acc[r], false);
            }
        }
        if (cell == 0) {
#pragma unroll
            for (int r = 0; r < 8; ++r) GN(kh, r, col) = acc[r];
        } else {
#pragma unroll
            for (int r = 0; r < 8; ++r) GS(kh, r, col) = acc[r];
        }
    }
    __syncthreads();

    // ---- epilogue A: combine gates (2 k's per thread); pack hnew for phase B ----
    if (tid < 512) {
        const int cell = tid >> 8;
        const int w = tid & 255;
        const int r = w >> 5, pr = w & 31;
        const int k0 = 2 * pr;
        const int row = r0 + r;
        if (cell == 0) {
            float gi0 = GN(0, r, k0) + GN(1, r, k0);
            float gi1 = GN(0, r, k0 + 1) + GN(1, r, k0 + 1);
            float gf0 = GN(0, r, 64 + k0) + GN(1, r, 64 + k0);
            float gf1 = GN(0, r, 64 + k0 + 1) + GN(1, r, 64 + k0 + 1);
            float gu0 = GN(0, r, 128 + k0) + GN(1, r, 128 + k0);
            float gu1 = GN(0, r, 128 + k0 + 1) + GN(1, r, 128 + k0 + 1);
            float go0 = GN(0, r, 192 + k0) + GN(1, r, 192 + k0);
            float go1 = GN(0, r, 192 + k0 + 1) + GN(1, r, 192 + k0 + 1);
            float2 cold = *(const float2*)(cn + row * 64 + k0);
            float c20 = sigm(gf0) * cold.x + sigm(gi0) * tanh_(gu0);
            float c21 = sigm(gf1) * cold.y + sigm(gi1) * tanh_(gu1);
            float h20 = sigm(go0) * tanh_(c20);
            float h21 = sigm(go1) * tanh_(c21);
            *(float2*)(cn + row * 64 + k0) = float2{c20, c21};
            *(float2*)(hnN + row * 64 + k0) = float2{h20, h21};
            sh_hnewp[r][pr] = pack2(h20, h21);
        } else {
            float gi0 = GS(0, r, k0) + GS(1, r, k0);
            float gi1 = GS(0, r, k0 + 1) + GS(1, r, k0 + 1);
            float gf0 = GS(0, r, 64 + k0) + GS(1, r, 64 + k0);
            float gf1 = GS(0, r, 64 + k0 + 1) + GS(1, r, 64 + k0 + 1);
            float gu0 = GS(0, r, 128 + k0) + GS(1, r, 128 + k0);
            float gu1 = GS(0, r, 128 + k0 + 1) + GS(1, r, 128 + k0 + 1);
            float go0 = GS(0, r, 192 + k0) + GS(1, r, 192 + k0);
            float go1 = GS(0, r, 192 + k0 + 1) + GS(1, r, 192 + k0 + 1);
            float2 cold = *(const float2*)(cs + row * 64 + k0);
            float c20 = sigm(gf0) * cold.x + sigm(gi0) * tanh_(gu0);
            float c21 = sigm(gf1) * cold.y + sigm(gi1) * tanh_(gu1);
            float h20 = sigm(go0) * tanh_(c20);
            float h21 = sigm(go1) * tanh_(c21);
            *(float2*)(cs + row * 64 + k0) = float2{c20, c21};
            *(float2*)(hsN + row * 64 + k0) = float2{h20, h21};
            sh_hnewp[r][32 + pr] = pack2(h20, h21);
        }
    }
    __syncthreads();

    // ---- phase B: d-cell gate GEMM. q=tid>>8 (dWx,dWh,dWa,dWb); 2 cols/thread, full K ----
    {
        const int q = tid >> 8;
        const int c0 = (tid & 255) * 2;
        int hp[8];
        if (q == 0) {
#pragma unroll
            for (int rr = 0; rr < 8; ++rr) hp[rr] = (int)sh_hnewp[rr][lane];
        } else if (q == 1) {
#pragma unroll
            for (int rr = 0; rr < 8; ++rr) hp[rr] = (int)sh_hdp[rr + 1][lane];
        } else if (q == 2) {
#pragma unroll
            for (int rr = 0; rr < 8; ++rr) hp[rr] = (int)sh_hdp[rr + 2][lane];
        } else {
#pragma unroll
            for (int rr = 0; rr < 8; ++rr) hp[rr] = (int)sh_hdp[rr][lane];
        }
        float acc0[8], acc1[8];
        float b0 = (q == 0) ? db[c0] : 0.f;
        float b1 = (q == 0) ? db[c0 + 1] : 0.f;
#pragma unroll
        for (int r = 0; r < 8; ++r) { acc0[r] = b0; acc1[r] = b1; }
        const unsigned int* PD = dpk + q * (64 * 512);
#pragma unroll 4
        for (int kk = 0; kk < 64; ++kk) {
            uint2 w = *(const uint2*)(PD + kk * 512 + c0);
            half2_t w0 = u2h(w.x), w1 = u2h(w.y);
#pragma unroll
            for (int rr = 0; rr < 8; ++rr) {
                half2_t hv = rdl_h2(hp[rr], kk);
                acc0[rr] = __builtin_amdgcn_fdot2(hv, w0, acc0[rr], false);
                acc1[rr] = __builtin_amdgcn_fdot2(hv, w1, acc1[rr], false);
            }
        }
#pragma unroll
        for (int r = 0; r < 8; ++r)
            *(float2*)&GD(q, r, c0) = float2{acc0[r], acc1[r]};
    }
    __syncthreads();

    // ---- epilogue B: d-cell gate combine (1024 items = 8 rows x 128) ----
    {
        const int r = tid >> 7, k = tid & 127;
        const int row = r0 + r;
        float gi = GD(0, r, k)       + GD(1, r, k)       + GD(2, r, k)       + GD(3, r, k);
        float gf = GD(0, r, 128 + k) + GD(1, r, 128 + k) + GD(2, r, 128 + k) + GD(3, r, 128 + k);
        float gu = GD(0, r, 256 + k) + GD(1, r, 256 + k) + GD(2, r, 256 + k) + GD(3, r, 256 + k);
        float go = GD(0, r, 384 + k) + GD(1, r, 384 + k) + GD(2, r, 384 + k) + GD(3, r, 384 + k);
        float c2 = sigm(gf) * cd[row * 128 + k] + sigm(gi) * tanh_(gu);
        float h2 = sigm(go) * tanh_(c2);
        cd[row * 128 + k] = c2; hdN[row * 128 + k] = h2; sh_hdnew[r][k] = h2;
    }
    __syncthreads();

    // ---- output heads: one wave per (row, head) ----
    {
        int p = tid >> 6;              // 0..15
        int r = p >> 1, head = p & 1;
        const float* W = head ? osW : onW;
        float partial = sh_hdnew[r][lane] * W[lane] + sh_hdnew[r][64 + lane] * W[64 + lane];
#pragma unroll
        for (int off = 32; off; off >>= 1) partial += __shfl_down(partial, off);
        if (lane == 0) outs[(t * ROWS + (r0 + r)) * 2 + head] = partial + (head ? osb[0] : onb[0]);
    }
#undef GN
#undef GS
#undef GD
}

// Assemble data outputs for t in [20,126] from stored head outputs.
__global__ __launch_bounds__(256) void assemble_kernel(
    const float* __restrict__ input, const float* __restrict__ ws, float* __restrict__ out)
{
    const float* outs = ws + OFF_OUTS;
    int idx = blockIdx.x * 256 + threadIdx.x;  // (b, tt, s)
    if (idx >= B_ * TOUT * S_) return;
    int s = idx & 127;
    int tmp = idx >> 7;
    int tt = tmp % TOUT;
    int b = tmp / TOUT;
    int t = tt + TPRED;
    int row = b * S_ + s;
    float o0 = outs[(t * ROWS + row) * 2 + 0];
    float o1 = outs[(t * ROWS + row) * 2 + 1];
    float inflow = (s == 0) ? input[(((b * T_) + (t + 1)) * S_ + 0) * 4 + 1]
                            : outs[(t * ROWS + row - 1) * 2 + 0];
    float numc = input[(((b * T_) + t) * S_ + s) * 4 + 2] + inflow - o0;
    float spd = (s == 0) ? input[(((b * T_) + (t + 1)) * S_ + 0) * 4 + 3] : o1;
    float4 v = make_float4(o0, inflow, numc, spd);
    reinterpret_cast<float4*>(out)[idx] = v;
}

extern "C" void kernel_launch(void* const* d_in, const int* in_sizes, int n_in,
                              void* d_out, int out_size, void* d_ws, size_t ws_size,
                              hipStream_t stream) {
    const float* input = (const float*)d_in[0];
    const float* nWx = (const float*)d_in[1];
    const float* nWh = (const float*)d_in[2];
    const float* nWa = (const float*)d_in[3];
    const float* nWb = (const float*)d_in[4];
    const float* nb  = (const float*)d_in[5];
    const float* sWx = (const float*)d_in[6];
    const float* sWh = (const float*)d_in[7];
    const float* sWa = (const float*)d_in[8];
    const float* sWb = (const float*)d_in[9];
    const float* sb  = (const float*)d_in[10];
    const float* dWx = (const float*)d_in[11];
    const float* dWh = (const float*)d_in[12];
    const float* dWa = (const float*)d_in[13];
    const float* dWb = (const float*)d_in[14];
    const float* db  = (const float*)d_in[15];
    const float* onW = (const float*)d_in[16];
    const float* onb = (const float*)d_in[17];
    const float* osW = (const float*)d_in[18];
    const float* osb = (const float*)d_in[19];

    float* ws = (float*)d_ws;

    // zero the recurrent state region (ws is poisoned 0xAA before every call)
    hipMemsetAsync(ws, 0, (size_t)STATE_FLOATS * sizeof(float), stream);

    // pack weights to fp16 pairs (same work every call; ~180K dwords)
    pack_weights<<<dim3((PACK_TOTAL + 255) / 256), dim3(256), 0, stream>>>(
        nWh, nWa, nWb, sWh, sWa, sWb, dWx, dWh, dWa, dWb, (unsigned int*)ws);

    for (int t = 0; t < NSTEPS; ++t) {
        step_kernel<<<dim3(NBLK), dim3(TB), 0, stream>>>(
            t, input, nWx, nb, sWx, sb, db, onW, onb, osW, osb, ws);
    }

    int nout = B_ * TOUT * S_;
    assemble_kernel<<<dim3((nout + 255) / 256), dim3(256), 0, stream>>>(input, ws, (float*)d_out);
}

// Round 6
// 1677.267 us; speedup vs baseline: 8.0434x; 2.1180x over previous
//
#include <hip/hip_runtime.h>

// Problem constants (from reference)
constexpr int B_ = 16, T_ = 128, S_ = 128;
constexpr int ROWS = B_ * S_;        // 2048
constexpr int NSTEPS = T_ - 1;       // 127
constexpr int TPRED = 20;
constexpr int TOUT = NSTEPS - TPRED; // 107
constexpr int RPB = 16;              // rows per block == MFMA M
constexpr int TB = 512;              // 8 waves
constexpr int NBLK = ROWS / RPB;     // 128 blocks

// ws layout in 4-byte units.
// h buffers are fp16 (2 halves per dword), c buffers fp32 in MFMA-lane order.
constexpr int OFF_HN = 0;                         // hn[2][2048][64] f16 -> 131072 dw
constexpr int OFF_HS = 131072;
constexpr int OFF_HD = 262144;                    // hd[2][2048][128] f16 -> 262144 dw
constexpr int OFF_CN = 524288;                    // cn[128*4][64][4] f32 (blk,wave,lane,reg)
constexpr int OFF_CS = 655360;
constexpr int OFF_CD = 786432;                    // cd[128*8][64][4] f32
constexpr int OFF_OUTS = 1048576;                 // outs[127][2048][2] f32
constexpr int STATE_DWORDS = OFF_OUTS;            // zero region (h fp16 + c fp32)
// packed fp16 weight fragments
constexpr int OFF_NPK = OFF_OUTS + NSTEPS * ROWS * 2;  // 1568768; 16 nt * 7 tiles * 256 dw
constexpr int NPK_DW = 16 * 7 * 256;                   // 28672
constexpr int OFF_SPK = OFF_NPK + NPK_DW;
constexpr int OFF_DPK = OFF_SPK + NPK_DW;              // 32 nt * 16 tiles * 256 dw
constexpr int DPK_DW = 32 * 16 * 256;                  // 131072
constexpr int PACK_DWORDS = 2 * NPK_DW + DPK_DW;       // 188416

typedef _Float16 half8 __attribute__((ext_vector_type(8)));
typedef float float4v __attribute__((ext_vector_type(4)));

__device__ __forceinline__ float sigm(float x) { return 1.f / (1.f + __expf(-x)); }
__device__ __forceinline__ float tanh_(float x) { return 2.f / (1.f + __expf(-2.f * x)) - 1.f; }
__device__ __forceinline__ unsigned int pack2(float a, float b) {
    union { unsigned int u; _Float16 h[2]; } x;
    x.h[0] = (_Float16)a; x.h[1] = (_Float16)b; return x.u;
}

// ---- pack fp32 weights into MFMA B-fragment tiles (fp16), once per call ----
// B-frag for 16x16x32: lane l holds B[k=(l>>4)*8+j][n=l&15], j=0..7 -> tile = 512 f16 = 256 dw.
// n/s packs: per nt(16): [Wh kt0, Wh kt1, Wa kt0, Wa kt1, Wb kt0, Wb kt1, Xaug]
//   n-Xaug rows: k=0..2 -> nWx, k=3 -> nb, else 0.  s-Xaug rows: k=4 -> sWx, k=5 -> sb, else 0.
// d pack: per nt(32): [dWx kt0..3, dWh kt0..3, dWa kt0..3, dWb kt0..3]
__global__ __launch_bounds__(256) void pack_weights(
    const float* __restrict__ nWx, const float* __restrict__ nWh,
    const float* __restrict__ nWa, const float* __restrict__ nWb, const float* __restrict__ nb,
    const float* __restrict__ sWx, const float* __restrict__ sWh,
    const float* __restrict__ sWa, const float* __restrict__ sWb, const float* __restrict__ sb,
    const float* __restrict__ dWx, const float* __restrict__ dWh,
    const float* __restrict__ dWa, const float* __restrict__ dWb,
    unsigned int* __restrict__ wsu)
{
    int idx = blockIdx.x * 256 + threadIdx.x;
    if (idx >= PACK_DWORDS) return;
    if (idx < 2 * NPK_DW) {
        bool isS = idx >= NPK_DW;
        int dn = isS ? idx - NPK_DW : idx;
        int tile = dn >> 8;
        int e = (dn & 255) * 2;           // half index in tile (even)
        int lane = e >> 3, j0 = e & 7;
        int quad = lane >> 4;
        int nt = tile / 7, tt = tile % 7;
        int col = nt * 16 + (lane & 15);
        float v0, v1;
        if (tt < 6) {
            const float* W = isS ? ((tt < 2) ? sWh : (tt < 4) ? sWa : sWb)
                                 : ((tt < 2) ? nWh : (tt < 4) ? nWa : nWb);
            int k = (tt & 1) * 32 + quad * 8 + j0;
            v0 = W[k * 256 + col]; v1 = W[(k + 1) * 256 + col];
        } else {
            int kl = quad * 8 + j0;
            auto xv = [&](int k) -> float {
                if (!isS) { if (k < 3) return nWx[k * 256 + col]; if (k == 3) return nb[col]; return 0.f; }
                else      { if (k == 4) return sWx[col]; if (k == 5) return sb[col]; return 0.f; }
            };
            v0 = xv(kl); v1 = xv(kl + 1);
        }
        wsu[(isS ? OFF_SPK : OFF_NPK) + dn] = pack2(v0, v1);
    } else {
        int dd = idx - 2 * NPK_DW;
        int tile = dd >> 8;
        int e = (dd & 255) * 2;
        int lane = e >> 3, j0 = e & 7;
        int quad = lane >> 4;
        int nt = tile >> 4, tt = tile & 15;
        const float* W = (tt < 4) ? dWx : (tt < 8) ? dWh : (tt < 12) ? dWa : dWb;
        int k = (tt & 3) * 32 + quad * 8 + j0;
        int col = nt * 16 + (lane & 15);
        wsu[OFF_DPK + dd] = pack2(W[k * 512 + col], W[(k + 1) * 512 + col]);
    }
}

__global__ __launch_bounds__(TB) void step_kernel(
    int t,
    const float* __restrict__ input,
    const float* __restrict__ db,
    const float* __restrict__ onW, const float* __restrict__ onb,
    const float* __restrict__ osW, const float* __restrict__ osb,
    float* __restrict__ ws)
{
    const int cur = t & 1, nxt = cur ^ 1;
    _Float16* hnB = (_Float16*)((unsigned int*)ws + OFF_HN);
    _Float16* hsB = (_Float16*)((unsigned int*)ws + OFF_HS);
    _Float16* hdB = (_Float16*)((unsigned int*)ws + OFF_HD);
    const _Float16* hnC = hnB + cur * ROWS * 64;
    const _Float16* hsC = hsB + cur * ROWS * 64;
    const _Float16* hdC = hdB + cur * ROWS * 128;
    _Float16* hnN = hnB + nxt * ROWS * 64;
    _Float16* hsN = hsB + nxt * ROWS * 64;
    _Float16* hdN = hdB + nxt * ROWS * 128;
    float* cn = ws + OFF_CN;
    float* cs = ws + OFF_CS;
    float* cd = ws + OFF_CD;
    float* outs = ws + OFF_OUTS;

    const int tid = threadIdx.x;
    const int wave = tid >> 6, lane = tid & 63;
    const int quad = lane >> 4, l15 = lane & 15;
    const int blk = blockIdx.x;
    const int r0 = blk * RPB;
    const int b = r0 >> 7;
    const int s0 = r0 & (S_ - 1);
    const bool leftOK = ((blk & 7) != 0);
    const bool rightOK = ((blk & 7) != 7);

    // padded fp16 LDS tiles (row strides keep 16B alignment + 2-way-max bank aliasing)
    __shared__ __align__(16) _Float16 sh_hn[18 * 72];
    __shared__ __align__(16) _Float16 sh_hs[18 * 72];
    __shared__ __align__(16) _Float16 sh_hd[18 * 136];
    __shared__ __align__(16) _Float16 sh_xa[16 * 40];   // x_aug: [x0,x1,x2,1,x3,1,0...]
    __shared__ __align__(16) _Float16 sh_dec[16 * 136]; // dec_in fp16 (phase-B A operand)
    __shared__ float sh_hdnew[16 * 128];                // fp32 for heads

    // ---- stage h (+halo) as dwords into padded LDS; build x_aug ----
    for (int i = tid; i < 2304; i += TB) {
        if (i < 576) {
            int row = i >> 5, p = i & 31;
            int grow = r0 + row - 1;
            bool v = (row == 0) ? leftOK : ((row == 17) ? rightOK : true);
            unsigned int val = v ? ((const unsigned int*)hnC)[grow * 32 + p] : 0u;
            *(unsigned int*)(sh_hn + row * 72 + 2 * p) = val;
        } else if (i < 1152) {
            int j = i - 576;
            int row = j >> 5, p = j & 31;
            int grow = r0 + row - 1;
            bool v = (row == 0) ? leftOK : ((row == 17) ? rightOK : true);
            unsigned int val = v ? ((const unsigned int*)hsC)[grow * 32 + p] : 0u;
            *(unsigned int*)(sh_hs + row * 72 + 2 * p) = val;
        } else {
            int j = i - 1152;
            int row = j >> 6, p = j & 63;
            int grow = r0 + row - 1;
            bool v = (row == 0) ? leftOK : ((row == 17) ? rightOK : true);
            unsigned int val = v ? ((const unsigned int*)hdC)[grow * 64 + p] : 0u;
            *(unsigned int*)(sh_hd + row * 136 + 2 * p) = val;
        }
    }
    // x_aug zero tail (dwords 3..19 of each 20-dword row) then head fill (dwords 0..2)
    for (int i = tid; i < 272; i += TB) {
        int r = i / 17, d = 3 + (i % 17);
        ((unsigned int*)sh_xa)[r * 20 + d] = 0u;
    }
    if (tid < 16) {
        const float* xp = input + ((size_t)(b * T_ + t) * S_ + (s0 + tid)) * 4;
        unsigned int* row = (unsigned int*)sh_xa + tid * 20;
        row[0] = pack2(xp[0], xp[1]);
        row[1] = pack2(xp[2], 1.f);
        row[2] = pack2(xp[3], 1.f);
    }
    __syncthreads();

    // ---- phase A: n-cell (waves 0-3) and s-cell (waves 4-7) via MFMA ----
    {
        const int w = wave & 3;
        const bool isS = (wave >= 4);
        const _Float16* hb = isS ? sh_hs : sh_hn;
        // A-frags: A[m=l15][k=quad*8+j]; row shift: Wh->+1 (self), Wa->+2 (s+1), Wb->+0 (s-1)
        half8 ah0 = *(const half8*)(hb + (l15 + 1) * 72 + quad * 8);
        half8 ah1 = *(const half8*)(hb + (l15 + 1) * 72 + 32 + quad * 8);
        half8 aa0 = *(const half8*)(hb + (l15 + 2) * 72 + quad * 8);
        half8 aa1 = *(const half8*)(hb + (l15 + 2) * 72 + 32 + quad * 8);
        half8 ab0 = *(const half8*)(hb + (l15) * 72 + quad * 8);
        half8 ab1 = *(const half8*)(hb + (l15) * 72 + 32 + quad * 8);
        half8 ax  = *(const half8*)(sh_xa + l15 * 40 + quad * 8);
        const _Float16* pk = (const _Float16*)((const unsigned int*)ws + (isS ? OFF_SPK : OFF_NPK));
        float4v acc[4];
#pragma unroll
        for (int i = 0; i < 4; ++i) acc[i] = (float4v){0.f, 0.f, 0.f, 0.f};
#pragma unroll
        for (int i = 0; i < 4; ++i) {   // nt = w + 4*i  (i-gate, f, u, o)
            const _Float16* base = pk + (size_t)(w + 4 * i) * 7 * 512 + lane * 8;
            half8 b0 = *(const half8*)(base);
            half8 b1 = *(const half8*)(base + 512);
            half8 b2 = *(const half8*)(base + 1024);
            half8 b3 = *(const half8*)(base + 1536);
            half8 b4 = *(const half8*)(base + 2048);
            half8 b5 = *(const half8*)(base + 2560);
            half8 b6 = *(const half8*)(base + 3072);
            acc[i] = __builtin_amdgcn_mfma_f32_16x16x32_f16(ah0, b0, acc[i], 0, 0, 0);
            acc[i] = __builtin_amdgcn_mfma_f32_16x16x32_f16(ah1, b1, acc[i], 0, 0, 0);
            acc[i] = __builtin_amdgcn_mfma_f32_16x16x32_f16(aa0, b2, acc[i], 0, 0, 0);
            acc[i] = __builtin_amdgcn_mfma_f32_16x16x32_f16(aa1, b3, acc[i], 0, 0, 0);
            acc[i] = __builtin_amdgcn_mfma_f32_16x16x32_f16(ab0, b4, acc[i], 0, 0, 0);
            acc[i] = __builtin_amdgcn_mfma_f32_16x16x32_f16(ab1, b5, acc[i], 0, 0, 0);
            acc[i] = __builtin_amdgcn_mfma_f32_16x16x32_f16(ax,  b6, acc[i], 0, 0, 0);
        }
        // in-register epilogue: C layout row=quad*4+r, col=l15; gate col k = 16w+l15
        float* cPtr = (isS ? cs : cn) + ((size_t)(blk * 4 + w) * 64 + lane) * 4;
        float4v cold = *(float4v*)cPtr, cnew;
        _Float16* hN = isS ? hsN : hnN;
        const int kcol = 16 * w + l15;
#pragma unroll
        for (int r = 0; r < 4; ++r) {
            float c2 = sigm(acc[1][r]) * cold[r] + sigm(acc[0][r]) * tanh_(acc[2][r]);
            float h2 = sigm(acc[3][r]) * tanh_(c2);
            cnew[r] = c2;
            int row = quad * 4 + r;
            hN[(size_t)(r0 + row) * 64 + kcol] = (_Float16)h2;
            sh_dec[row * 136 + (isS ? 64 : 0) + kcol] = (_Float16)h2;
        }
        *(float4v*)cPtr = cnew;
    }
    __syncthreads();

    // ---- phase B: d-cell via MFMA (all 8 waves) ----
    {
        half8 aD[4], aWh[4], aWa[4], aWb[4];
#pragma unroll
        for (int kt = 0; kt < 4; ++kt) {
            aD[kt]  = *(const half8*)(sh_dec + l15 * 136 + kt * 32 + quad * 8);
            aWh[kt] = *(const half8*)(sh_hd + (l15 + 1) * 136 + kt * 32 + quad * 8);
            aWa[kt] = *(const half8*)(sh_hd + (l15 + 2) * 136 + kt * 32 + quad * 8);
            aWb[kt] = *(const half8*)(sh_hd + (l15) * 136 + kt * 32 + quad * 8);
        }
        const _Float16* pd = (const _Float16*)((const unsigned int*)ws + OFF_DPK);
        float4v acc[4];
#pragma unroll
        for (int i = 0; i < 4; ++i) acc[i] = (float4v){0.f, 0.f, 0.f, 0.f};
#pragma unroll
        for (int i = 0; i < 4; ++i) {   // nt = wave + 8*i
            const _Float16* base = pd + (size_t)(wave + 8 * i) * 16 * 512 + lane * 8;
#pragma unroll
            for (int kt = 0; kt < 4; ++kt)
                acc[i] = __builtin_amdgcn_mfma_f32_16x16x32_f16(aD[kt], *(const half8*)(base + kt * 512), acc[i], 0, 0, 0);
#pragma unroll
            for (int kt = 0; kt < 4; ++kt)
                acc[i] = __builtin_amdgcn_mfma_f32_16x16x32_f16(aWh[kt], *(const half8*)(base + (4 + kt) * 512), acc[i], 0, 0, 0);
#pragma unroll
            for (int kt = 0; kt < 4; ++kt)
                acc[i] = __builtin_amdgcn_mfma_f32_16x16x32_f16(aWa[kt], *(const half8*)(base + (8 + kt) * 512), acc[i], 0, 0, 0);
#pragma unroll
            for (int kt = 0; kt < 4; ++kt)
                acc[i] = __builtin_amdgcn_mfma_f32_16x16x32_f16(aWb[kt], *(const half8*)(base + (12 + kt) * 512), acc[i], 0, 0, 0);
        }
        const int kd = 16 * wave + l15;
        float bi = db[kd], bf = db[128 + kd], bu = db[256 + kd], bo = db[384 + kd];
        float* cPtr = cd + ((size_t)(blk * 8 + wave) * 64 + lane) * 4;
        float4v cold = *(float4v*)cPtr, cnew;
#pragma unroll
        for (int r = 0; r < 4; ++r) {
            float c2 = sigm(acc[1][r] + bf) * cold[r] + sigm(acc[0][r] + bi) * tanh_(acc[2][r] + bu);
            float h2 = sigm(acc[3][r] + bo) * tanh_(c2);
            cnew[r] = c2;
            int row = quad * 4 + r;
            hdN[(size_t)(r0 + row) * 128 + kd] = (_Float16)h2;
            sh_hdnew[row * 128 + kd] = h2;
        }
        *(float4v*)cPtr = cnew;
    }
    __syncthreads();

    // ---- output heads: 32 (row,head) pairs x 16 lanes ----
    {
        int p = tid >> 4, l16 = tid & 15;
        int row = p >> 1, head = p & 1;
        const float* W = head ? osW : onW;
        float partial = 0.f;
#pragma unroll
        for (int k = 0; k < 128; k += 16) partial += sh_hdnew[row * 128 + k + l16] * W[k + l16];
#pragma unroll
        for (int off = 8; off; off >>= 1) partial += __shfl_down(partial, off, 16);
        if (l16 == 0) outs[((size_t)t * ROWS + (r0 + row)) * 2 + head] = partial + (head ? osb[0] : onb[0]);
    }
}

// Assemble data outputs for t in [20,126] from stored head outputs.
__global__ __launch_bounds__(256) void assemble_kernel(
    const float* __restrict__ input, const float* __restrict__ ws, float* __restrict__ out)
{
    const float* outs = ws + OFF_OUTS;
    int idx = blockIdx.x * 256 + threadIdx.x;  // (b, tt, s)
    if (idx >= B_ * TOUT * S_) return;
    int s = idx & 127;
    int tmp = idx >> 7;
    int tt = tmp % TOUT;
    int b = tmp / TOUT;
    int t = tt + TPRED;
    int row = b * S_ + s;
    float o0 = outs[((size_t)t * ROWS + row) * 2 + 0];
    float o1 = outs[((size_t)t * ROWS + row) * 2 + 1];
    float inflow = (s == 0) ? input[(((size_t)b * T_ + (t + 1)) * S_ + 0) * 4 + 1]
                            : outs[((size_t)t * ROWS + row - 1) * 2 + 0];
    float numc = input[(((size_t)b * T_ + t) * S_ + s) * 4 + 2] + inflow - o0;
    float spd = (s == 0) ? input[(((size_t)b * T_ + (t + 1)) * S_ + 0) * 4 + 3] : o1;
    float4 v = make_float4(o0, inflow, numc, spd);
    reinterpret_cast<float4*>(out)[idx] = v;
}

extern "C" void kernel_launch(void* const* d_in, const int* in_sizes, int n_in,
                              void* d_out, int out_size, void* d_ws, size_t ws_size,
                              hipStream_t stream) {
    const float* input = (const float*)d_in[0];
    const float* nWx = (const float*)d_in[1];
    const float* nWh = (const float*)d_in[2];
    const float* nWa = (const float*)d_in[3];
    const float* nWb = (const float*)d_in[4];
    const float* nb  = (const float*)d_in[5];
    const float* sWx = (const float*)d_in[6];
    const float* sWh = (const float*)d_in[7];
    const float* sWa = (const float*)d_in[8];
    const float* sWb = (const float*)d_in[9];
    const float* sb  = (const float*)d_in[10];
    const float* dWx = (const float*)d_in[11];
    const float* dWh = (const float*)d_in[12];
    const float* dWa = (const float*)d_in[13];
    const float* dWb = (const float*)d_in[14];
    const float* db  = (const float*)d_in[15];
    const float* onW = (const float*)d_in[16];
    const float* onb = (const float*)d_in[17];
    const float* osW = (const float*)d_in[18];
    const float* osb = (const float*)d_in[19];

    float* ws = (float*)d_ws;

    // zero recurrent state (h fp16 + c fp32); ws is poisoned 0xAA before every call
    hipMemsetAsync(ws, 0, (size_t)STATE_DWORDS * 4, stream);

    // pack weights into MFMA B-fragment tiles (once per call)
    pack_weights<<<dim3((PACK_DWORDS + 255) / 256), dim3(256), 0, stream>>>(
        nWx, nWh, nWa, nWb, nb, sWx, sWh, sWa, sWb, sb,
        dWx, dWh, dWa, dWb, (unsigned int*)ws);

    for (int t = 0; t < NSTEPS; ++t) {
        step_kernel<<<dim3(NBLK), dim3(TB), 0, stream>>>(
            t, input, db, onW, onb, osW, osb, ws);
    }

    int nout = B_ * TOUT * S_;
    assemble_kernel<<<dim3((nout + 255) / 256), dim3(256), 0, stream>>>(input, ws, (float*)d_out);
}